// Round 2
// baseline (57.282 us; speedup 1.0000x reference)
//
#include <hip/hip_runtime.h>
#include <hip/hip_cooperative_groups.h>
#include <math.h>

namespace cg = cooperative_groups;

// Problem constants (match reference)
constexpr int S = 128;
constexpr int B = 2;
constexpr int M = 1024;
constexpr int C = 80;
constexpr int P = S * S * B;        // 32768
constexpr int NPROB = S * S * C;    // 1310720
constexpr int NPROB4 = NPROB / 4;   // 327680
constexpr float LAMBDA_COORD = 5.0f;
constexpr float LAMBDA_NO_OBJ = 0.5f;

constexpr int GRID = 512;
constexpr int BLOCK = 256;

__device__ __forceinline__ float nn_sqrt(float x) {
    float s = sqrtf(x);
    return isnan(s) ? 0.0f : s;   // jnp.nan_to_num(sqrt(x))
}

__device__ __forceinline__ float block_reduce(float acc, float* wsum) {
    #pragma unroll
    for (int off = 32; off > 0; off >>= 1)
        acc += __shfl_down(acc, off, 64);
    const int lane = threadIdx.x & 63;
    const int wid  = threadIdx.x >> 6;
    if (lane == 0) wsum[wid] = acc;
    __syncthreads();
    return wsum[0] + wsum[1] + wsum[2] + wsum[3];
}

__global__ void __launch_bounds__(BLOCK)
yolo_loss_coop(const float* __restrict__ main_boxes,   // [M,4]
               const float* __restrict__ pred_boxes,   // [P,4]
               const float* __restrict__ conf,         // [P]
               const float* __restrict__ gmp,          // [S*S*C]
               const float* __restrict__ gpp,          // [S*S*C]
               const int*   __restrict__ matched_main, // [P]
               const float* __restrict__ matched_iou,  // [P]
               float* __restrict__ out,
               float* __restrict__ ws)                 // >= GRID floats
{
    const int tid = blockIdx.x * BLOCK + threadIdx.x;
    const int nthreads = GRID * BLOCK;
    float acc = 0.0f;

    // ---- box loss over P predictions ----
    const float4* pb4 = reinterpret_cast<const float4*>(pred_boxes);
    const float4* mb4 = reinterpret_cast<const float4*>(main_boxes);
    for (int p = tid; p < P; p += nthreads) {
        float c  = conf[p];
        int   mm = matched_main[p];
        if (mm >= 0) {
            float4 pb = pb4[p];
            float4 mb = mb4[mm];
            float dx = mb.x - pb.x;
            float dy = mb.y - pb.y;
            float xy = dx * dx + dy * dy;
            float dw = nn_sqrt(mb.z) - nn_sqrt(pb.z);
            float dh = nn_sqrt(mb.w) - nn_sqrt(pb.w);
            float wh = dw * dw + dh * dh;
            float dc = matched_iou[p] - c;
            acc += LAMBDA_COORD * (xy + wh) + dc * dc;
        } else {
            acc += LAMBDA_NO_OBJ * c * c;
        }
    }

    // ---- prob loss over S*S*C, float4-vectorized ----
    const float4* g1 = reinterpret_cast<const float4*>(gmp);
    const float4* g2 = reinterpret_cast<const float4*>(gpp);
    for (int i = tid; i < NPROB4; i += nthreads) {
        float4 a = g1[i];
        float4 b = g2[i];
        float d0 = a.x - b.x, d1 = a.y - b.y, d2 = a.z - b.z, d3 = a.w - b.w;
        acc += d0 * d0 + d1 * d1 + d2 * d2 + d3 * d3;
    }

    // ---- block reduction -> one partial per block ----
    __shared__ float wsum[BLOCK / 64];
    float bsum = block_reduce(acc, wsum);
    if (threadIdx.x == 0) ws[blockIdx.x] = bsum;

    // ---- grid-wide sync, then block 0 folds the partials ----
    cg::this_grid().sync();

    if (blockIdx.x == 0) {
        // 256 threads each own 2 of the 512 partials
        float v = ws[threadIdx.x] + ws[threadIdx.x + BLOCK];
        float total = block_reduce(v, wsum);
        if (threadIdx.x == 0) out[0] = total;
    }
}

// Fallback (2-dispatch) path in case ws is unusably small: memset + atomics.
__global__ void __launch_bounds__(BLOCK)
yolo_loss_atomic(const float* __restrict__ main_boxes,
                 const float* __restrict__ pred_boxes,
                 const float* __restrict__ conf,
                 const float* __restrict__ gmp,
                 const float* __restrict__ gpp,
                 const int*   __restrict__ matched_main,
                 const float* __restrict__ matched_iou,
                 float* __restrict__ out)
{
    const int tid = blockIdx.x * BLOCK + threadIdx.x;
    const int nthreads = GRID * BLOCK;
    float acc = 0.0f;
    const float4* pb4 = reinterpret_cast<const float4*>(pred_boxes);
    const float4* mb4 = reinterpret_cast<const float4*>(main_boxes);
    for (int p = tid; p < P; p += nthreads) {
        float c  = conf[p];
        int   mm = matched_main[p];
        if (mm >= 0) {
            float4 pb = pb4[p];
            float4 mb = mb4[mm];
            float dx = mb.x - pb.x;
            float dy = mb.y - pb.y;
            float xy = dx * dx + dy * dy;
            float dw = nn_sqrt(mb.z) - nn_sqrt(pb.z);
            float dh = nn_sqrt(mb.w) - nn_sqrt(pb.w);
            float wh = dw * dw + dh * dh;
            float dc = matched_iou[p] - c;
            acc += LAMBDA_COORD * (xy + wh) + dc * dc;
        } else {
            acc += LAMBDA_NO_OBJ * c * c;
        }
    }
    const float4* g1 = reinterpret_cast<const float4*>(gmp);
    const float4* g2 = reinterpret_cast<const float4*>(gpp);
    for (int i = tid; i < NPROB4; i += nthreads) {
        float4 a = g1[i];
        float4 b = g2[i];
        float d0 = a.x - b.x, d1 = a.y - b.y, d2 = a.z - b.z, d3 = a.w - b.w;
        acc += d0 * d0 + d1 * d1 + d2 * d2 + d3 * d3;
    }
    __shared__ float wsum[BLOCK / 64];
    float bsum = block_reduce(acc, wsum);
    if (threadIdx.x == 0) atomicAdd(out, bsum);
}

extern "C" void kernel_launch(void* const* d_in, const int* in_sizes, int n_in,
                              void* d_out, int out_size, void* d_ws, size_t ws_size,
                              hipStream_t stream) {
    const float* main_boxes   = (const float*)d_in[0];
    const float* pred_boxes   = (const float*)d_in[1];
    const float* conf         = (const float*)d_in[2];
    const float* gmp          = (const float*)d_in[3];
    const float* gpp          = (const float*)d_in[4];
    const int*   matched_main = (const int*)d_in[5];
    const float* matched_iou  = (const float*)d_in[6];
    float* out = (float*)d_out;
    float* ws  = (float*)d_ws;

    if (ws_size >= GRID * sizeof(float)) {
        void* args[] = {
            (void*)&main_boxes, (void*)&pred_boxes, (void*)&conf,
            (void*)&gmp, (void*)&gpp, (void*)&matched_main,
            (void*)&matched_iou, (void*)&out, (void*)&ws,
        };
        hipLaunchCooperativeKernel((const void*)yolo_loss_coop,
                                   dim3(GRID), dim3(BLOCK), args, 0, stream);
    } else {
        hipMemsetAsync(out, 0, sizeof(float), stream);
        yolo_loss_atomic<<<GRID, BLOCK, 0, stream>>>(
            main_boxes, pred_boxes, conf, gmp, gpp, matched_main, matched_iou, out);
    }
}

// Round 3
// 12.016 us; speedup vs baseline: 4.7672x; 4.7672x over previous
//
#include <hip/hip_runtime.h>
#include <math.h>

// Problem constants (match reference)
constexpr int S = 128;
constexpr int B = 2;
constexpr int M = 1024;
constexpr int C = 80;
constexpr int P = S * S * B;        // 32768
constexpr int NPROB = S * S * C;    // 1310720
constexpr int NPROB4 = NPROB / 4;   // 327680
constexpr float LAMBDA_COORD = 5.0f;
constexpr float LAMBDA_NO_OBJ = 0.5f;

constexpr int GRID = 512;
constexpr int BLOCK = 256;

__device__ __forceinline__ float nn_sqrt(float x) {
    float s = sqrtf(x);
    return isnan(s) ? 0.0f : s;   // jnp.nan_to_num(sqrt(x))
}

__device__ __forceinline__ float block_reduce(float acc, float* wsum) {
    #pragma unroll
    for (int off = 32; off > 0; off >>= 1)
        acc += __shfl_down(acc, off, 64);
    const int lane = threadIdx.x & 63;
    const int wid  = threadIdx.x >> 6;
    if (lane == 0) wsum[wid] = acc;
    __syncthreads();
    return wsum[0] + wsum[1] + wsum[2] + wsum[3];
}

// Kernel 1: each block writes its partial sum to ws[blockIdx.x] (plain store).
__global__ void __launch_bounds__(BLOCK)
yolo_loss_partials(const float* __restrict__ main_boxes,   // [M,4]
                   const float* __restrict__ pred_boxes,   // [P,4]
                   const float* __restrict__ conf,         // [P]
                   const float* __restrict__ gmp,          // [S*S*C]
                   const float* __restrict__ gpp,          // [S*S*C]
                   const int*   __restrict__ matched_main, // [P]
                   const float* __restrict__ matched_iou,  // [P]
                   float* __restrict__ ws)                 // >= GRID floats
{
    const int tid = blockIdx.x * BLOCK + threadIdx.x;
    const int nthreads = GRID * BLOCK;
    float acc = 0.0f;

    // ---- box loss over P predictions ----
    const float4* pb4 = reinterpret_cast<const float4*>(pred_boxes);
    const float4* mb4 = reinterpret_cast<const float4*>(main_boxes);
    for (int p = tid; p < P; p += nthreads) {
        float c  = conf[p];
        int   mm = matched_main[p];
        if (mm >= 0) {
            float4 pb = pb4[p];
            float4 mb = mb4[mm];
            float dx = mb.x - pb.x;
            float dy = mb.y - pb.y;
            float xy = dx * dx + dy * dy;
            float dw = nn_sqrt(mb.z) - nn_sqrt(pb.z);
            float dh = nn_sqrt(mb.w) - nn_sqrt(pb.w);
            float wh = dw * dw + dh * dh;
            float dc = matched_iou[p] - c;
            acc += LAMBDA_COORD * (xy + wh) + dc * dc;
        } else {
            acc += LAMBDA_NO_OBJ * c * c;
        }
    }

    // ---- prob loss over S*S*C, float4-vectorized ----
    const float4* g1 = reinterpret_cast<const float4*>(gmp);
    const float4* g2 = reinterpret_cast<const float4*>(gpp);
    for (int i = tid; i < NPROB4; i += nthreads) {
        float4 a = g1[i];
        float4 b = g2[i];
        float d0 = a.x - b.x, d1 = a.y - b.y, d2 = a.z - b.z, d3 = a.w - b.w;
        acc += d0 * d0 + d1 * d1 + d2 * d2 + d3 * d3;
    }

    __shared__ float wsum[BLOCK / 64];
    float bsum = block_reduce(acc, wsum);
    if (threadIdx.x == 0) ws[blockIdx.x] = bsum;
}

// Kernel 2: one block folds GRID partials and stores the scalar.
__global__ void __launch_bounds__(BLOCK)
yolo_loss_finalize(const float* __restrict__ ws, float* __restrict__ out)
{
    float v = ws[threadIdx.x] + ws[threadIdx.x + BLOCK];  // 512 -> 256
    __shared__ float wsum[BLOCK / 64];
    float total = block_reduce(v, wsum);
    if (threadIdx.x == 0) out[0] = total;
}

// Fallback if ws is unusably small: memset + atomic accumulate.
__global__ void __launch_bounds__(BLOCK)
yolo_loss_atomic(const float* __restrict__ main_boxes,
                 const float* __restrict__ pred_boxes,
                 const float* __restrict__ conf,
                 const float* __restrict__ gmp,
                 const float* __restrict__ gpp,
                 const int*   __restrict__ matched_main,
                 const float* __restrict__ matched_iou,
                 float* __restrict__ out)
{
    const int tid = blockIdx.x * BLOCK + threadIdx.x;
    const int nthreads = GRID * BLOCK;
    float acc = 0.0f;
    const float4* pb4 = reinterpret_cast<const float4*>(pred_boxes);
    const float4* mb4 = reinterpret_cast<const float4*>(main_boxes);
    for (int p = tid; p < P; p += nthreads) {
        float c  = conf[p];
        int   mm = matched_main[p];
        if (mm >= 0) {
            float4 pb = pb4[p];
            float4 mb = mb4[mm];
            float dx = mb.x - pb.x;
            float dy = mb.y - pb.y;
            float xy = dx * dx + dy * dy;
            float dw = nn_sqrt(mb.z) - nn_sqrt(pb.z);
            float dh = nn_sqrt(mb.w) - nn_sqrt(pb.w);
            float wh = dw * dw + dh * dh;
            float dc = matched_iou[p] - c;
            acc += LAMBDA_COORD * (xy + wh) + dc * dc;
        } else {
            acc += LAMBDA_NO_OBJ * c * c;
        }
    }
    const float4* g1 = reinterpret_cast<const float4*>(gmp);
    const float4* g2 = reinterpret_cast<const float4*>(gpp);
    for (int i = tid; i < NPROB4; i += nthreads) {
        float4 a = g1[i];
        float4 b = g2[i];
        float d0 = a.x - b.x, d1 = a.y - b.y, d2 = a.z - b.z, d3 = a.w - b.w;
        acc += d0 * d0 + d1 * d1 + d2 * d2 + d3 * d3;
    }
    __shared__ float wsum[BLOCK / 64];
    float bsum = block_reduce(acc, wsum);
    if (threadIdx.x == 0) atomicAdd(out, bsum);
}

extern "C" void kernel_launch(void* const* d_in, const int* in_sizes, int n_in,
                              void* d_out, int out_size, void* d_ws, size_t ws_size,
                              hipStream_t stream) {
    const float* main_boxes   = (const float*)d_in[0];
    const float* pred_boxes   = (const float*)d_in[1];
    const float* conf         = (const float*)d_in[2];
    const float* gmp          = (const float*)d_in[3];
    const float* gpp          = (const float*)d_in[4];
    const int*   matched_main = (const int*)d_in[5];
    const float* matched_iou  = (const float*)d_in[6];
    float* out = (float*)d_out;
    float* ws  = (float*)d_ws;

    if (ws_size >= GRID * sizeof(float)) {
        yolo_loss_partials<<<GRID, BLOCK, 0, stream>>>(
            main_boxes, pred_boxes, conf, gmp, gpp, matched_main, matched_iou, ws);
        yolo_loss_finalize<<<1, BLOCK, 0, stream>>>(ws, out);
    } else {
        hipMemsetAsync(out, 0, sizeof(float), stream);
        yolo_loss_atomic<<<GRID, BLOCK, 0, stream>>>(
            main_boxes, pred_boxes, conf, gmp, gpp, matched_main, matched_iou, out);
    }
}

// Round 4
// 11.598 us; speedup vs baseline: 4.9388x; 1.0360x over previous
//
#include <hip/hip_runtime.h>
#include <math.h>

// Problem constants (match reference)
constexpr int S = 128;
constexpr int B = 2;
constexpr int M = 1024;
constexpr int C = 80;
constexpr int P = S * S * B;        // 32768
constexpr int NPROB = S * S * C;    // 1310720
constexpr int NPROB4 = NPROB / 4;   // 327680
constexpr float LAMBDA_COORD = 5.0f;
constexpr float LAMBDA_NO_OBJ = 0.5f;

constexpr int BLOCK = 256;
constexpr int GRID = NPROB4 / BLOCK;   // 1280: one float4 prob iter per thread
constexpr int FIN_THREADS = 64;        // one wave

__device__ __forceinline__ float nn_sqrt(float x) {
    float s = sqrtf(x);
    return isnan(s) ? 0.0f : s;   // jnp.nan_to_num(sqrt(x))
}

__device__ __forceinline__ float wave_reduce(float acc) {
    #pragma unroll
    for (int off = 32; off > 0; off >>= 1)
        acc += __shfl_down(acc, off, 64);
    return acc;
}

// Kernel 1: each block writes its partial sum to ws[blockIdx.x] (plain store).
__global__ void __launch_bounds__(BLOCK)
yolo_loss_partials(const float* __restrict__ main_boxes,   // [M,4]
                   const float* __restrict__ pred_boxes,   // [P,4]
                   const float* __restrict__ conf,         // [P]
                   const float* __restrict__ gmp,          // [S*S*C]
                   const float* __restrict__ gpp,          // [S*S*C]
                   const int*   __restrict__ matched_main, // [P]
                   const float* __restrict__ matched_iou,  // [P]
                   float* __restrict__ ws)                 // >= GRID floats
{
    const int tid = blockIdx.x * BLOCK + threadIdx.x;
    float acc = 0.0f;

    // ---- prob loss: exactly one float4 per thread ----
    {
        const float4* g1 = reinterpret_cast<const float4*>(gmp);
        const float4* g2 = reinterpret_cast<const float4*>(gpp);
        float4 a = g1[tid];
        float4 b = g2[tid];
        float d0 = a.x - b.x, d1 = a.y - b.y, d2 = a.z - b.z, d3 = a.w - b.w;
        acc = d0 * d0 + d1 * d1 + d2 * d2 + d3 * d3;
    }

    // ---- box loss: first P threads take one prediction each ----
    if (tid < P) {
        const float4* pb4 = reinterpret_cast<const float4*>(pred_boxes);
        const float4* mb4 = reinterpret_cast<const float4*>(main_boxes);
        float c  = conf[tid];
        int   mm = matched_main[tid];
        if (mm >= 0) {
            float4 pb = pb4[tid];
            float4 mb = mb4[mm];
            float dx = mb.x - pb.x;
            float dy = mb.y - pb.y;
            float xy = dx * dx + dy * dy;
            float dw = nn_sqrt(mb.z) - nn_sqrt(pb.z);
            float dh = nn_sqrt(mb.w) - nn_sqrt(pb.w);
            float wh = dw * dw + dh * dh;
            float dc = matched_iou[tid] - c;
            acc += LAMBDA_COORD * (xy + wh) + dc * dc;
        } else {
            acc += LAMBDA_NO_OBJ * c * c;
        }
    }

    // ---- block reduction -> one partial per block ----
    float wacc = wave_reduce(acc);
    __shared__ float wsum[BLOCK / 64];
    const int lane = threadIdx.x & 63;
    const int wid  = threadIdx.x >> 6;
    if (lane == 0) wsum[wid] = wacc;
    __syncthreads();
    if (threadIdx.x == 0)
        ws[blockIdx.x] = wsum[0] + wsum[1] + wsum[2] + wsum[3];
}

// Kernel 2: one wave folds GRID partials and stores the scalar.
__global__ void __launch_bounds__(FIN_THREADS)
yolo_loss_finalize(const float* __restrict__ ws, float* __restrict__ out)
{
    const float4* w4 = reinterpret_cast<const float4*>(ws);
    constexpr int N4 = GRID / 4;              // 320 float4
    constexpr int PER = N4 / FIN_THREADS;     // 5 per lane
    float acc = 0.0f;
    #pragma unroll
    for (int k = 0; k < PER; ++k) {
        float4 v = w4[threadIdx.x + k * FIN_THREADS];
        acc += v.x + v.y + v.z + v.w;
    }
    float total = wave_reduce(acc);
    if (threadIdx.x == 0) out[0] = total;
}

// Fallback if ws is unusably small: memset + atomic accumulate.
__global__ void __launch_bounds__(BLOCK)
yolo_loss_atomic(const float* __restrict__ main_boxes,
                 const float* __restrict__ pred_boxes,
                 const float* __restrict__ conf,
                 const float* __restrict__ gmp,
                 const float* __restrict__ gpp,
                 const int*   __restrict__ matched_main,
                 const float* __restrict__ matched_iou,
                 float* __restrict__ out)
{
    const int tid = blockIdx.x * BLOCK + threadIdx.x;
    const int nthreads = GRID * BLOCK;
    float acc = 0.0f;
    const float4* pb4 = reinterpret_cast<const float4*>(pred_boxes);
    const float4* mb4 = reinterpret_cast<const float4*>(main_boxes);
    for (int p = tid; p < P; p += nthreads) {
        float c  = conf[p];
        int   mm = matched_main[p];
        if (mm >= 0) {
            float4 pb = pb4[p];
            float4 mb = mb4[mm];
            float dx = mb.x - pb.x;
            float dy = mb.y - pb.y;
            float xy = dx * dx + dy * dy;
            float dw = nn_sqrt(mb.z) - nn_sqrt(pb.z);
            float dh = nn_sqrt(mb.w) - nn_sqrt(pb.w);
            float wh = dw * dw + dh * dh;
            float dc = matched_iou[p] - c;
            acc += LAMBDA_COORD * (xy + wh) + dc * dc;
        } else {
            acc += LAMBDA_NO_OBJ * c * c;
        }
    }
    const float4* g1 = reinterpret_cast<const float4*>(gmp);
    const float4* g2 = reinterpret_cast<const float4*>(gpp);
    for (int i = tid; i < NPROB4; i += nthreads) {
        float4 a = g1[i];
        float4 b = g2[i];
        float d0 = a.x - b.x, d1 = a.y - b.y, d2 = a.z - b.z, d3 = a.w - b.w;
        acc += d0 * d0 + d1 * d1 + d2 * d2 + d3 * d3;
    }
    float wacc = wave_reduce(acc);
    __shared__ float wsum[BLOCK / 64];
    const int lane = threadIdx.x & 63;
    const int wid  = threadIdx.x >> 6;
    if (lane == 0) wsum[wid] = wacc;
    __syncthreads();
    if (threadIdx.x == 0)
        atomicAdd(out, wsum[0] + wsum[1] + wsum[2] + wsum[3]);
}

extern "C" void kernel_launch(void* const* d_in, const int* in_sizes, int n_in,
                              void* d_out, int out_size, void* d_ws, size_t ws_size,
                              hipStream_t stream) {
    const float* main_boxes   = (const float*)d_in[0];
    const float* pred_boxes   = (const float*)d_in[1];
    const float* conf         = (const float*)d_in[2];
    const float* gmp          = (const float*)d_in[3];
    const float* gpp          = (const float*)d_in[4];
    const int*   matched_main = (const int*)d_in[5];
    const float* matched_iou  = (const float*)d_in[6];
    float* out = (float*)d_out;
    float* ws  = (float*)d_ws;

    if (ws_size >= GRID * sizeof(float)) {
        yolo_loss_partials<<<GRID, BLOCK, 0, stream>>>(
            main_boxes, pred_boxes, conf, gmp, gpp, matched_main, matched_iou, ws);
        yolo_loss_finalize<<<1, FIN_THREADS, 0, stream>>>(ws, out);
    } else {
        hipMemsetAsync(out, 0, sizeof(float), stream);
        yolo_loss_atomic<<<GRID, BLOCK, 0, stream>>>(
            main_boxes, pred_boxes, conf, gmp, gpp, matched_main, matched_iou, out);
    }
}